// Round 8
// baseline (291.444 us; speedup 1.0000x reference)
//
#include <hip/hip_runtime.h>
#include <hip/hip_bf16.h>
#include <cstdint>

typedef __bf16 bf16x8 __attribute__((ext_vector_type(8)));
typedef float f32x4 __attribute__((ext_vector_type(4)));

// ---------- helpers ----------
__device__ __forceinline__ unsigned short f2bf(float f) {
  union { float f; uint32_t u; } a; a.f = f;
  uint32_t r = a.u + 0x7fffu + ((a.u >> 16) & 1u);
  return (unsigned short)(r >> 16);
}
__device__ __forceinline__ void gload_lds16(const unsigned short* g, unsigned short* l) {
  __builtin_amdgcn_global_load_lds(
      (const __attribute__((address_space(1))) void*)g,
      (__attribute__((address_space(3))) void*)l, 16, 0, 0);
}

// ---------- merged cast kernel ----------
// blocks 0..4095: x fp32 -> bf16 (8 elems/thread)
// blocks 4096..7167: W[3][1024][1024] fp32 -> Wt[3][e][d] bf16 (transpose)
__global__ void cast_all(const float* __restrict__ x, const float* __restrict__ W,
                         unsigned short* __restrict__ xb, unsigned short* __restrict__ Wt) {
  __shared__ float tile[32][33];
  const int bx = blockIdx.x;
  const int t = threadIdx.x;
  if (bx < 4096) {
    size_t i = ((size_t)bx * 256 + t) * 8;
    float4 a = *(const float4*)(x + i);
    float4 b = *(const float4*)(x + i + 4);
    uint4 o;
    o.x = (uint32_t)f2bf(a.x) | ((uint32_t)f2bf(a.y) << 16);
    o.y = (uint32_t)f2bf(a.z) | ((uint32_t)f2bf(a.w) << 16);
    o.z = (uint32_t)f2bf(b.x) | ((uint32_t)f2bf(b.y) << 16);
    o.w = (uint32_t)f2bf(b.z) | ((uint32_t)f2bf(b.w) << 16);
    *(uint4*)(xb + i) = o;
  } else {
    const int b = bx - 4096;              // 0..3071
    const int z = b >> 10;
    const int rest = b & 1023;
    const int bxx = rest & 31, byy = rest >> 5;
    const float* Wz = W + (size_t)z * 1048576;
    unsigned short* Wtz = Wt + (size_t)z * 1048576;
    const int x0 = bxx * 32, y0 = byy * 32;
    const int tx = t & 31, ty = t >> 5;
#pragma unroll
    for (int i = 0; i < 32; i += 8)
      tile[ty + i][tx] = Wz[(size_t)(y0 + ty + i) * 1024 + x0 + tx];
    __syncthreads();
#pragma unroll
    for (int i = 0; i < 32; i += 8)
      Wtz[(size_t)(x0 + ty + i) * 1024 + y0 + tx] = f2bf(tile[tx][ty + i]);
  }
}

// ---------- GEMM: C[m,n] = A[m,:] . Bt[n,:] ----------
// Tiles 128 x (NJ*32), BK=32, double-buffered LDS (one barrier per K-step;
// next tile's global_load_lds issued before compute). XOR-swizzled LDS
// (conflict-free, verified R1: SQ_LDS_BANK_CONFLICT 4.2e6 -> 0).
// Single instantiation of the K-loop per kernel (VGPR 72 — R6's wrapper
// doubled it to 144; keep this shape).
// Grids are 3D with x = mt fastest (XCD L2 locality — R6's linear decode
// cost 41->203 MB FETCH; keep this mapping).
// MODE 4 = merged QKV (NJ=4): z=0,1 -> bf16 C + z*sC; z=2 -> Vt[b][e][s]
// MODE 5 = scores (NJ=4): exp(acc/32) -> bf16 P_un + partial rowsums to aux
// MODE 6 = PV (NJ=2, BN=64): out = acc / rowsum (sum of 32 partials)
template <int MODE, int NJ>
__global__ void __launch_bounds__(256)
gemm_bt(const unsigned short* __restrict__ Aall,
        const unsigned short* __restrict__ Btall,
        void* __restrict__ Call, unsigned short* __restrict__ VtPtr,
        float* __restrict__ aux,
        int K, int ldc, long sA, long sB, long sC, float scale) {
  __shared__ unsigned short As[2][4096];
  __shared__ unsigned short Bs[2][4096];
  const int t = threadIdx.x;
  const int lane = t & 63;
  const int quad = lane >> 4;
  const int l15 = lane & 15;
  const int wave = t >> 6;
  const int wm = (wave >> 1) * 64;
  const int wn = (wave & 1) * (NJ * 16);
  const int z = blockIdx.z;

  const unsigned short* A = Aall + (size_t)z * sA + (size_t)blockIdx.x * 128 * K;
  const unsigned short* Bt = Btall + (size_t)z * sB + (size_t)blockIdx.y * (NJ * 32) * K;

  const int srow = t >> 2;                             // 0..63
  const int scol = (((t & 3) ^ ((srow >> 1) & 3)) * 8);
  const unsigned short* ga = A + (size_t)srow * K + scol;
  const unsigned short* gb = Bt + (size_t)srow * K + scol;
  const size_t rowskip = (size_t)64 * K;

  const int swz = (quad ^ ((l15 >> 1) & 3)) * 8;
  const int aOff = (wm + l15) * 32 + swz;
  const int bOff = (wn + l15) * 32 + swz;

  f32x4 acc[4][NJ];
#pragma unroll
  for (int i = 0; i < 4; i++)
#pragma unroll
    for (int j = 0; j < NJ; j++) acc[i][j] = (f32x4){0.f, 0.f, 0.f, 0.f};

  gload_lds16(ga, &As[0][t * 8]);
  gload_lds16(ga + rowskip, &As[0][2048 + t * 8]);
  gload_lds16(gb, &Bs[0][t * 8]);
  if (NJ == 4) gload_lds16(gb + rowskip, &Bs[0][2048 + t * 8]);

  int buf = 0;
  for (int k0 = 0; k0 < K; k0 += 32, buf ^= 1) {
    __syncthreads();
    if (k0 + 32 < K) {
      const int kn = k0 + 32;
      gload_lds16(ga + kn, &As[buf ^ 1][t * 8]);
      gload_lds16(ga + rowskip + kn, &As[buf ^ 1][2048 + t * 8]);
      gload_lds16(gb + kn, &Bs[buf ^ 1][t * 8]);
      if (NJ == 4) gload_lds16(gb + rowskip + kn, &Bs[buf ^ 1][2048 + t * 8]);
    }
    const unsigned short* aB = &As[buf][aOff];
    const unsigned short* bB = &Bs[buf][bOff];
    bf16x8 a[4], b[NJ];
#pragma unroll
    for (int i = 0; i < 4; i++) a[i] = *(const bf16x8*)(aB + i * 512);
#pragma unroll
    for (int j = 0; j < NJ; j++) b[j] = *(const bf16x8*)(bB + j * 512);
#pragma unroll
    for (int i = 0; i < 4; i++)
#pragma unroll
      for (int j = 0; j < NJ; j++)
        acc[i][j] = __builtin_amdgcn_mfma_f32_16x16x32_bf16(a[i], b[j], acc[i][j], 0, 0, 0);
  }

  // C/D layout: col = lane&15, row = quad*4 + reg  [verified m89/m91]
  const int mbase = blockIdx.x * 128 + wm + quad * 4;
  const int nbase = blockIdx.y * (NJ * 32) + wn + l15;

  if (MODE == 4) {
    if (z < 2) {
      unsigned short* C = (unsigned short*)Call + (size_t)z * sC;
#pragma unroll
      for (int mi = 0; mi < 4; mi++)
#pragma unroll
        for (int ni = 0; ni < NJ; ni++) {
          const int m = mbase + mi * 16, n = nbase + ni * 16;
#pragma unroll
          for (int r = 0; r < 4; r++)
            C[(size_t)(m + r) * ldc + n] = f2bf(acc[mi][ni][r]);
        }
    } else {  // z==2: Vt[b][e=n][s] <- acc, m = b*2048 + s
      unsigned short* C = VtPtr;
#pragma unroll
      for (int mi = 0; mi < 4; mi++) {
        const int m = mbase + mi * 16;
        const int b = m >> 11, s = m & 2047;
#pragma unroll
        for (int ni = 0; ni < NJ; ni++) {
          const int n = nbase + ni * 16;
          uint2 val;
          val.x = (uint32_t)f2bf(acc[mi][ni][0]) | ((uint32_t)f2bf(acc[mi][ni][1]) << 16);
          val.y = (uint32_t)f2bf(acc[mi][ni][2]) | ((uint32_t)f2bf(acc[mi][ni][3]) << 16);
          *(uint2*)(C + (size_t)b * 2097152 + (size_t)n * 2048 + s) = val;
        }
      }
    }
  } else if (MODE == 5) {
    // exp + store P_un + per-row partial sums
    unsigned short* C = (unsigned short*)Call + (size_t)z * sC;
    const int j = blockIdx.y * 2 + (wave & 1);
#pragma unroll
    for (int mi = 0; mi < 4; mi++) {
#pragma unroll
      for (int r = 0; r < 4; r++) {
        const int m = mbase + mi * 16 + r;
        float s = 0.f;
#pragma unroll
        for (int ni = 0; ni < NJ; ni++) {
          const float e = __expf(acc[mi][ni][r] * scale);
          C[(size_t)m * ldc + nbase + ni * 16] = f2bf(e);
          s += e;
        }
        s += __shfl_xor(s, 1);
        s += __shfl_xor(s, 2);
        s += __shfl_xor(s, 4);
        s += __shfl_xor(s, 8);
        if (l15 == 0) aux[(size_t)j * 8192 + (size_t)z * 2048 + m] = s;
      }
    }
  } else {  // MODE 6: PV + normalize (NJ=2, BN=64)
    float* C = (float*)Call + (size_t)z * sC;
#pragma unroll
    for (int mi = 0; mi < 4; mi++) {
#pragma unroll
      for (int r = 0; r < 4; r++) {
        const int m = mbase + mi * 16 + r;
        const size_t grow = (size_t)z * 2048 + m;
        float tot = 0.f;
#pragma unroll
        for (int j = 0; j < 32; j++) tot += aux[(size_t)j * 8192 + grow];
        const float inv = 1.f / tot;
#pragma unroll
        for (int ni = 0; ni < NJ; ni++)
          C[(size_t)m * ldc + nbase + ni * 16] = acc[mi][ni][r] * inv;
      }
    }
  }
}

// ---------- launcher ----------
// B=4, S=2048, D=1024. Workspace (102 MB):
//   xb @0: 16MB | Wt @16MB: 6MB (dead after QKV; partial[32][8192] overlays it)
//   Q @22MB: 16MB | K @38MB: 16MB | Vt @54MB: 16MB [4][e][s]
//   Sb @70MB: 32MB P_unnorm bf16 [4][2048][2048]
extern "C" void kernel_launch(void* const* d_in, const int* in_sizes, int n_in,
                              void* d_out, int out_size, void* d_ws, size_t ws_size,
                              hipStream_t stream) {
  const float* x = (const float*)d_in[0];
  const float* W = (const float*)d_in[1];
  float* out = (float*)d_out;
  char* ws = (char*)d_ws;
  unsigned short* xb = (unsigned short*)(ws);
  unsigned short* Wt = (unsigned short*)(ws + (16ll << 20));
  float* partial     = (float*)(ws + (16ll << 20));   // overlays Wt after QKV
  unsigned short* Q  = (unsigned short*)(ws + (22ll << 20));
  unsigned short* Kb = (unsigned short*)(ws + (38ll << 20));
  unsigned short* Vt = (unsigned short*)(ws + (54ll << 20));
  unsigned short* Sb = (unsigned short*)(ws + (70ll << 20));

  cast_all<<<7168, 256, 0, stream>>>(x, W, xb, Wt);

  // merged QKV projection: z=0 -> Q, z=1 -> K, z=2 -> Vt (transposed store)
  gemm_bt<4, 4><<<dim3(64, 8, 3), 256, 0, stream>>>(
      xb, Wt, Q, Vt, nullptr, 1024, 1024, 0L, 1048576L, 8388608L, 1.0f);
  // P_un = exp(Q K^T / 32), bf16, + per-row partial sums into `partial`
  gemm_bt<5, 4><<<dim3(16, 16, 4), 256, 0, stream>>>(
      Q, Kb, Sb, nullptr, partial, 1024, 2048, 2097152L, 2097152L, 4194304L, 0.03125f);
  // out = (P_un @ V) / rowsum, BN=64 tiles -> 1024 blocks (4/CU)
  gemm_bt<6, 2><<<dim3(16, 16, 4), 256, 0, stream>>>(
      Sb, Vt, out, nullptr, partial, 2048, 1024, 4194304L, 2097152L, 2097152L, 1.0f);
}

// Round 9
// 277.005 us; speedup vs baseline: 1.0521x; 1.0521x over previous
//
#include <hip/hip_runtime.h>
#include <hip/hip_bf16.h>
#include <cstdint>

typedef __bf16 bf16x8 __attribute__((ext_vector_type(8)));
typedef float f32x4 __attribute__((ext_vector_type(4)));

// ---------- helpers ----------
__device__ __forceinline__ unsigned short f2bf(float f) {
  union { float f; uint32_t u; } a; a.f = f;
  uint32_t r = a.u + 0x7fffu + ((a.u >> 16) & 1u);
  return (unsigned short)(r >> 16);
}
__device__ __forceinline__ void gload_lds16(const unsigned short* g, unsigned short* l) {
  __builtin_amdgcn_global_load_lds(
      (const __attribute__((address_space(1))) void*)g,
      (__attribute__((address_space(3))) void*)l, 16, 0, 0);
}

// ---------- merged cast kernel ----------
// blocks 0..4095: x fp32 -> bf16 (8 elems/thread)
// blocks 4096..7167: W[3][1024][1024] fp32 -> Wt[3][e][d] bf16 (transpose)
__global__ void cast_all(const float* __restrict__ x, const float* __restrict__ W,
                         unsigned short* __restrict__ xb, unsigned short* __restrict__ Wt) {
  __shared__ float tile[32][33];
  const int bx = blockIdx.x;
  const int t = threadIdx.x;
  if (bx < 4096) {
    size_t i = ((size_t)bx * 256 + t) * 8;
    float4 a = *(const float4*)(x + i);
    float4 b = *(const float4*)(x + i + 4);
    uint4 o;
    o.x = (uint32_t)f2bf(a.x) | ((uint32_t)f2bf(a.y) << 16);
    o.y = (uint32_t)f2bf(a.z) | ((uint32_t)f2bf(a.w) << 16);
    o.z = (uint32_t)f2bf(b.x) | ((uint32_t)f2bf(b.y) << 16);
    o.w = (uint32_t)f2bf(b.z) | ((uint32_t)f2bf(b.w) << 16);
    *(uint4*)(xb + i) = o;
  } else {
    const int b = bx - 4096;              // 0..3071
    const int z = b >> 10;
    const int rest = b & 1023;
    const int bxx = rest & 31, byy = rest >> 5;
    const float* Wz = W + (size_t)z * 1048576;
    unsigned short* Wtz = Wt + (size_t)z * 1048576;
    const int x0 = bxx * 32, y0 = byy * 32;
    const int tx = t & 31, ty = t >> 5;
#pragma unroll
    for (int i = 0; i < 32; i += 8)
      tile[ty + i][tx] = Wz[(size_t)(y0 + ty + i) * 1024 + x0 + tx];
    __syncthreads();
#pragma unroll
    for (int i = 0; i < 32; i += 8)
      Wtz[(size_t)(x0 + ty + i) * 1024 + y0 + tx] = f2bf(tile[tx][ty + i]);
  }
}

// ---------- GEMM: C[m,n] = A[m,:] . Bt[n,:] ----------
// Tiles 128x128 (NJ=4 everywhere — BN=64 regressed in R7: VGPR 108, 2 blk/CU,
// 2x A-traffic), BK=32, double-buffered LDS, XOR-swizzled (conflict-free, R1).
// Grids 3D, x = mt fastest (XCD L2 locality — R6 lost 41->203 MB FETCH).
// __launch_bounds__(256,4): force 64 arch-VGPR + 64 AGPR = 128 total ->
// 4 waves/SIMD (4 blocks/CU), up from 136 regs / 3 blocks/CU. [R8 experiment]
// MODE 4 = merged QKV: z=0,1 -> bf16 C + z*sC; z=2 -> Vt[b][e][s]
// MODE 5 = scores: exp(acc/32) -> bf16 P_un + partial rowsums to aux
// MODE 6 = PV: out = acc / rowsum (sum of 32 partials)
template <int MODE, int NJ>
__global__ void __launch_bounds__(256, 4)
gemm_bt(const unsigned short* __restrict__ Aall,
        const unsigned short* __restrict__ Btall,
        void* __restrict__ Call, unsigned short* __restrict__ VtPtr,
        float* __restrict__ aux,
        int K, int ldc, long sA, long sB, long sC, float scale) {
  __shared__ unsigned short As[2][4096];
  __shared__ unsigned short Bs[2][4096];
  const int t = threadIdx.x;
  const int lane = t & 63;
  const int quad = lane >> 4;
  const int l15 = lane & 15;
  const int wave = t >> 6;
  const int wm = (wave >> 1) * 64;
  const int wn = (wave & 1) * (NJ * 16);
  const int z = blockIdx.z;

  const unsigned short* A = Aall + (size_t)z * sA + (size_t)blockIdx.x * 128 * K;
  const unsigned short* Bt = Btall + (size_t)z * sB + (size_t)blockIdx.y * (NJ * 32) * K;

  const int srow = t >> 2;                             // 0..63
  const int scol = (((t & 3) ^ ((srow >> 1) & 3)) * 8);
  const unsigned short* ga = A + (size_t)srow * K + scol;
  const unsigned short* gb = Bt + (size_t)srow * K + scol;
  const size_t rowskip = (size_t)64 * K;

  const int swz = (quad ^ ((l15 >> 1) & 3)) * 8;
  const int aOff = (wm + l15) * 32 + swz;
  const int bOff = (wn + l15) * 32 + swz;

  f32x4 acc[4][NJ];
#pragma unroll
  for (int i = 0; i < 4; i++)
#pragma unroll
    for (int j = 0; j < NJ; j++) acc[i][j] = (f32x4){0.f, 0.f, 0.f, 0.f};

  gload_lds16(ga, &As[0][t * 8]);
  gload_lds16(ga + rowskip, &As[0][2048 + t * 8]);
  gload_lds16(gb, &Bs[0][t * 8]);
  if (NJ == 4) gload_lds16(gb + rowskip, &Bs[0][2048 + t * 8]);

  int buf = 0;
  for (int k0 = 0; k0 < K; k0 += 32, buf ^= 1) {
    __syncthreads();
    if (k0 + 32 < K) {
      const int kn = k0 + 32;
      gload_lds16(ga + kn, &As[buf ^ 1][t * 8]);
      gload_lds16(ga + rowskip + kn, &As[buf ^ 1][2048 + t * 8]);
      gload_lds16(gb + kn, &Bs[buf ^ 1][t * 8]);
      if (NJ == 4) gload_lds16(gb + rowskip + kn, &Bs[buf ^ 1][2048 + t * 8]);
    }
    const unsigned short* aB = &As[buf][aOff];
    const unsigned short* bB = &Bs[buf][bOff];
    bf16x8 a[4], b[NJ];
#pragma unroll
    for (int i = 0; i < 4; i++) a[i] = *(const bf16x8*)(aB + i * 512);
#pragma unroll
    for (int j = 0; j < NJ; j++) b[j] = *(const bf16x8*)(bB + j * 512);
#pragma unroll
    for (int i = 0; i < 4; i++)
#pragma unroll
      for (int j = 0; j < NJ; j++)
        acc[i][j] = __builtin_amdgcn_mfma_f32_16x16x32_bf16(a[i], b[j], acc[i][j], 0, 0, 0);
  }

  // C/D layout: col = lane&15, row = quad*4 + reg  [verified m89/m91]
  const int mbase = blockIdx.x * 128 + wm + quad * 4;
  const int nbase = blockIdx.y * (NJ * 32) + wn + l15;

  if (MODE == 4) {
    if (z < 2) {
      unsigned short* C = (unsigned short*)Call + (size_t)z * sC;
#pragma unroll
      for (int mi = 0; mi < 4; mi++)
#pragma unroll
        for (int ni = 0; ni < NJ; ni++) {
          const int m = mbase + mi * 16, n = nbase + ni * 16;
#pragma unroll
          for (int r = 0; r < 4; r++)
            C[(size_t)(m + r) * ldc + n] = f2bf(acc[mi][ni][r]);
        }
    } else {  // z==2: Vt[b][e=n][s] <- acc, m = b*2048 + s
      unsigned short* C = VtPtr;
#pragma unroll
      for (int mi = 0; mi < 4; mi++) {
        const int m = mbase + mi * 16;
        const int b = m >> 11, s = m & 2047;
#pragma unroll
        for (int ni = 0; ni < NJ; ni++) {
          const int n = nbase + ni * 16;
          uint2 val;
          val.x = (uint32_t)f2bf(acc[mi][ni][0]) | ((uint32_t)f2bf(acc[mi][ni][1]) << 16);
          val.y = (uint32_t)f2bf(acc[mi][ni][2]) | ((uint32_t)f2bf(acc[mi][ni][3]) << 16);
          *(uint2*)(C + (size_t)b * 2097152 + (size_t)n * 2048 + s) = val;
        }
      }
    }
  } else if (MODE == 5) {
    // exp + store P_un + per-row partial sums
    unsigned short* C = (unsigned short*)Call + (size_t)z * sC;
    const int j = blockIdx.y * 2 + (wave & 1);
#pragma unroll
    for (int mi = 0; mi < 4; mi++) {
#pragma unroll
      for (int r = 0; r < 4; r++) {
        const int m = mbase + mi * 16 + r;
        float s = 0.f;
#pragma unroll
        for (int ni = 0; ni < NJ; ni++) {
          const float e = __expf(acc[mi][ni][r] * scale);
          C[(size_t)m * ldc + nbase + ni * 16] = f2bf(e);
          s += e;
        }
        s += __shfl_xor(s, 1);
        s += __shfl_xor(s, 2);
        s += __shfl_xor(s, 4);
        s += __shfl_xor(s, 8);
        if (l15 == 0) aux[(size_t)j * 8192 + (size_t)z * 2048 + m] = s;
      }
    }
  } else {  // MODE 6: PV + normalize
    float* C = (float*)Call + (size_t)z * sC;
#pragma unroll
    for (int mi = 0; mi < 4; mi++) {
#pragma unroll
      for (int r = 0; r < 4; r++) {
        const int m = mbase + mi * 16 + r;
        const size_t grow = (size_t)z * 2048 + m;
        float tot = 0.f;
#pragma unroll
        for (int j = 0; j < 32; j++) tot += aux[(size_t)j * 8192 + grow];
        const float inv = 1.f / tot;
#pragma unroll
        for (int ni = 0; ni < NJ; ni++)
          C[(size_t)m * ldc + nbase + ni * 16] = acc[mi][ni][r] * inv;
      }
    }
  }
}

// ---------- launcher ----------
// B=4, S=2048, D=1024. Workspace (102 MB):
//   xb @0: 16MB | Wt @16MB: 6MB (dead after QKV; partial[32][8192] overlays it)
//   Q @22MB: 16MB | K @38MB: 16MB | Vt @54MB: 16MB [4][e][s]
//   Sb @70MB: 32MB P_unnorm bf16 [4][2048][2048]
extern "C" void kernel_launch(void* const* d_in, const int* in_sizes, int n_in,
                              void* d_out, int out_size, void* d_ws, size_t ws_size,
                              hipStream_t stream) {
  const float* x = (const float*)d_in[0];
  const float* W = (const float*)d_in[1];
  float* out = (float*)d_out;
  char* ws = (char*)d_ws;
  unsigned short* xb = (unsigned short*)(ws);
  unsigned short* Wt = (unsigned short*)(ws + (16ll << 20));
  float* partial     = (float*)(ws + (16ll << 20));   // overlays Wt after QKV
  unsigned short* Q  = (unsigned short*)(ws + (22ll << 20));
  unsigned short* Kb = (unsigned short*)(ws + (38ll << 20));
  unsigned short* Vt = (unsigned short*)(ws + (54ll << 20));
  unsigned short* Sb = (unsigned short*)(ws + (70ll << 20));

  cast_all<<<7168, 256, 0, stream>>>(x, W, xb, Wt);

  // merged QKV projection: z=0 -> Q, z=1 -> K, z=2 -> Vt (transposed store)
  gemm_bt<4, 4><<<dim3(64, 8, 3), 256, 0, stream>>>(
      xb, Wt, Q, Vt, nullptr, 1024, 1024, 0L, 1048576L, 8388608L, 1.0f);
  // P_un = exp(Q K^T / 32), bf16, + per-row partial sums into `partial`
  gemm_bt<5, 4><<<dim3(16, 16, 4), 256, 0, stream>>>(
      Q, Kb, Sb, nullptr, partial, 1024, 2048, 2097152L, 2097152L, 4194304L, 0.03125f);
  // out = (P_un @ V) / rowsum, BN=128 (reverted from R7's BN=64 regression)
  gemm_bt<6, 4><<<dim3(16, 8, 4), 256, 0, stream>>>(
      Sb, Vt, out, nullptr, partial, 2048, 1024, 4194304L, 2097152L, 2097152L, 1.0f);
}